// Round 2
// baseline (732.862 us; speedup 1.0000x reference)
//
#include <hip/hip_runtime.h>

#define NSTEP 730
#define NGRID 10000

__global__ __launch_bounds__(64) void hbv_kernel(
    const float* __restrict__ x, const float* __restrict__ params,
    float* __restrict__ out)
{
    const int g = blockIdx.x * 64 + threadIdx.x;
    if (g >= NGRID) return;

    // parameters[-1]: last timestep slice, shape (NGRID, 12, 1)
    const long pbase = ((long)(NSTEP - 1) * NGRID + g) * 12;
    float pr[12];
#pragma unroll
    for (int i = 0; i < 12; ++i) pr[i] = params[pbase + i];

    const float lo[12] = {1.0f, 50.0f, 0.05f, 0.01f, 0.001f, 0.2f, 0.0f, 0.0f, -2.5f, 0.5f, 0.0f, 0.0f};
    const float hi[12] = {6.0f, 1000.0f, 0.9f, 0.5f, 0.2f, 1.0f, 10.0f, 100.0f, 2.5f, 10.0f, 0.1f, 0.2f};
    float ps[12];
#pragma unroll
    for (int i = 0; i < 12; ++i) ps[i] = lo[i] + pr[i] * (hi[i] - lo[i]);

    const float BETA = ps[0], FC = ps[1], K0 = ps[2], K1 = ps[3], K2 = ps[4], LP = ps[5],
                PERCmax = ps[6], UZL = ps[7], TT = ps[8], CFMAX = ps[9], CFR = ps[10], CWH = ps[11];

    // loop-invariant precomputes (remove all divides from the hot loop)
    const float rFC = 1.0f / FC;
    const float rLPFC = 1.0f / (LP * FC);
    const float CFRxCFMAX = CFR * CFMAX;

    float SNOWPACK = 0.001f, MELTWATER = 0.001f, SM = 0.001f, SUZ = 0.001f, SLZ = 0.001f;

    const float* xp = x + (long)g * 3;           // + t*NGRID*3 per step
    float* outQ = out + g;
    float* outE = out + (long)NSTEP * NGRID + g;
    float* outS = out + 2L * NSTEP * NGRID + g;

    // software-pipeline: prefetch next timestep's forcing while computing current
    float Pn = xp[0], Tn = xp[1], En = xp[2];

    for (int t = 0; t < NSTEP; ++t) {
        const float Pt = Pn, Tt = Tn, PETt = En;
        if (t + 1 < NSTEP) {
            const float* nx = xp + (long)(t + 1) * NGRID * 3;
            Pn = nx[0];
            Tn = nx[1];
            En = nx[2];
        }

        // snow routine
        const float RAIN = (Tt >= TT) ? Pt : 0.0f;
        const float SNOW = Pt - RAIN;
        SNOWPACK += SNOW;
        const float melt = fminf(fmaxf(CFMAX * (Tt - TT), 0.0f), SNOWPACK);
        MELTWATER += melt;
        SNOWPACK -= melt;
        const float refreeze = fminf(fmaxf(CFRxCFMAX * (TT - Tt), 0.0f), MELTWATER);
        SNOWPACK += refreeze;
        MELTWATER -= refreeze;
        const float tosoil = fmaxf(MELTWATER - CWH * SNOWPACK, 0.0f);
        MELTWATER -= tosoil;

        // soil routine: (SM/FC)^BETA via hw v_log_f32 / v_exp_f32 (both base-2)
        const float ratio = SM * rFC;
        float sw = __builtin_amdgcn_exp2f(BETA * __builtin_amdgcn_logf(ratio));
        sw = fminf(fmaxf(sw, 0.0f), 1.0f);
        const float rt = RAIN + tosoil;
        const float recharge = rt * sw;
        SM = SM + rt - recharge;
        const float excess = fmaxf(SM - FC, 0.0f);
        const float evapf = fminf(fmaxf(SM * rLPFC, 0.0f), 1.0f);
        const float ETact = fminf(SM, PETt * evapf);
        SM = fmaxf(SM - ETact, 1e-5f);

        // response routine
        SUZ = SUZ + recharge + excess;
        const float PERC = fminf(SUZ, PERCmax);
        SUZ -= PERC;
        const float Q0 = K0 * fmaxf(SUZ - UZL, 0.0f);
        SUZ -= Q0;
        const float Q1 = K1 * SUZ;
        SUZ -= Q1;
        SLZ += PERC;
        const float Q2 = K2 * SLZ;
        SLZ -= Q2;

        const long o = (long)t * NGRID;
        outQ[o] = Q0 + Q1 + Q2;
        outE[o] = ETact;
        outS[o] = SNOWPACK;
    }
}

extern "C" void kernel_launch(void* const* d_in, const int* in_sizes, int n_in,
                              void* d_out, int out_size, void* d_ws, size_t ws_size,
                              hipStream_t stream) {
    const float* x = (const float*)d_in[0];
    const float* params = (const float*)d_in[1];
    float* out = (float*)d_out;
    const int threads = 64;
    const int blocks = (NGRID + threads - 1) / threads;  // 157 blocks -> ~1 wave/CU
    hbv_kernel<<<blocks, threads, 0, stream>>>(x, params, out);
}

// Round 3
// 534.740 us; speedup vs baseline: 1.3705x; 1.3705x over previous
//
#include <hip/hip_runtime.h>

#define NSTEP 730
#define NGRID 10000
#define DPF 10   // prefetch depth; 730 % 10 == 0 -> 73 exact chunks

__global__ __launch_bounds__(64) void hbv_kernel(
    const float* __restrict__ x, const float* __restrict__ params,
    float* __restrict__ out)
{
    const int g = blockIdx.x * 64 + threadIdx.x;
    if (g >= NGRID) return;

    // parameters[-1]: last timestep slice, shape (NGRID, 12, 1)
    const long pbase = ((long)(NSTEP - 1) * NGRID + g) * 12;
    float pr[12];
#pragma unroll
    for (int i = 0; i < 12; ++i) pr[i] = params[pbase + i];

    const float lo[12] = {1.0f, 50.0f, 0.05f, 0.01f, 0.001f, 0.2f, 0.0f, 0.0f, -2.5f, 0.5f, 0.0f, 0.0f};
    const float hi[12] = {6.0f, 1000.0f, 0.9f, 0.5f, 0.2f, 1.0f, 10.0f, 100.0f, 2.5f, 10.0f, 0.1f, 0.2f};
    float ps[12];
#pragma unroll
    for (int i = 0; i < 12; ++i) ps[i] = lo[i] + pr[i] * (hi[i] - lo[i]);

    const float BETA = ps[0], FC = ps[1], K0 = ps[2], K1 = ps[3], K2 = ps[4], LP = ps[5],
                PERCmax = ps[6], UZL = ps[7], TT = ps[8], CFMAX = ps[9], CFR = ps[10], CWH = ps[11];

    const float rFC = 1.0f / FC;
    const float rLPFC = 1.0f / (LP * FC);
    const float CFRxCFMAX = CFR * CFMAX;

    float SNOWPACK = 0.001f, MELTWATER = 0.001f, SM = 0.001f, SUZ = 0.001f, SLZ = 0.001f;

    const float* xg = x + (long)g * 3;
    const long stepStride = (long)NGRID * 3;
    float* outQ = out + g;
    float* outE = out + (long)NSTEP * NGRID + g;
    float* outS = out + 2L * NSTEP * NGRID + g;

    // ---- deep software pipeline: D-step register ring ----
    float bP[DPF], bT[DPF], bE[DPF];
#pragma unroll
    for (int d = 0; d < DPF; ++d) {
        const float* p = xg + (long)d * stepStride;
        bP[d] = p[0]; bT[d] = p[1]; bE[d] = p[2];
    }

    for (int t0 = 0; t0 < NSTEP; t0 += DPF) {
        // issue ALL next-chunk loads up front (10 outstanding dwordx3 loads)
        float nP[DPF], nT[DPF], nE[DPF];
#pragma unroll
        for (int d = 0; d < DPF; ++d) {
            int tt = t0 + DPF + d;
            if (tt > NSTEP - 1) tt = NSTEP - 1;   // last chunk: clamp (values unused)
            const float* p = xg + (long)tt * stepStride;
            nP[d] = p[0]; nT[d] = p[1]; nE[d] = p[2];
        }

        // compute the current chunk's 10 steps (~1500 cyc) over the loads' latency
#pragma unroll
        for (int d = 0; d < DPF; ++d) {
            const float Pt = bP[d], Tt = bT[d], PETt = bE[d];

            // snow routine
            const float RAIN = (Tt >= TT) ? Pt : 0.0f;
            const float SNOW = Pt - RAIN;
            SNOWPACK += SNOW;
            const float melt = fminf(fmaxf(CFMAX * (Tt - TT), 0.0f), SNOWPACK);
            MELTWATER += melt;
            SNOWPACK -= melt;
            const float refreeze = fminf(fmaxf(CFRxCFMAX * (TT - Tt), 0.0f), MELTWATER);
            SNOWPACK += refreeze;
            MELTWATER -= refreeze;
            const float tosoil = fmaxf(MELTWATER - CWH * SNOWPACK, 0.0f);
            MELTWATER -= tosoil;

            // soil routine: (SM/FC)^BETA via hw v_log_f32 / v_exp_f32 (base-2)
            const float ratio = SM * rFC;
            float sw = __builtin_amdgcn_exp2f(BETA * __builtin_amdgcn_logf(ratio));
            sw = fminf(fmaxf(sw, 0.0f), 1.0f);
            const float rt = RAIN + tosoil;
            const float recharge = rt * sw;
            SM = SM + rt - recharge;
            const float excess = fmaxf(SM - FC, 0.0f);
            const float evapf = fminf(fmaxf(SM * rLPFC, 0.0f), 1.0f);
            const float ETact = fminf(SM, PETt * evapf);
            SM = fmaxf(SM - ETact, 1e-5f);

            // response routine
            SUZ = SUZ + recharge + excess;
            const float PERC = fminf(SUZ, PERCmax);
            SUZ -= PERC;
            const float Q0 = K0 * fmaxf(SUZ - UZL, 0.0f);
            SUZ -= Q0;
            const float Q1 = K1 * SUZ;
            SUZ -= Q1;
            SLZ += PERC;
            const float Q2 = K2 * SLZ;
            SLZ -= Q2;

            const long o = (long)(t0 + d) * NGRID;
            outQ[o] = Q0 + Q1 + Q2;
            outE[o] = ETact;
            outS[o] = SNOWPACK;
        }

        // rotate buffers
#pragma unroll
        for (int d = 0; d < DPF; ++d) { bP[d] = nP[d]; bT[d] = nT[d]; bE[d] = nE[d]; }
    }
}

extern "C" void kernel_launch(void* const* d_in, const int* in_sizes, int n_in,
                              void* d_out, int out_size, void* d_ws, size_t ws_size,
                              hipStream_t stream) {
    const float* x = (const float*)d_in[0];
    const float* params = (const float*)d_in[1];
    float* out = (float*)d_out;
    const int threads = 64;
    const int blocks = (NGRID + threads - 1) / threads;  // 157 blocks -> ~1 wave/CU
    hbv_kernel<<<blocks, threads, 0, stream>>>(x, params, out);
}